// Round 1
// baseline (71.861 us; speedup 1.0000x reference)
//
#include <hip/hip_runtime.h>
#include <math.h>

// Problem constants (from reference): B=4, T_TGT=256, T_SRC=512, H=1024, V=32100
#define NB 4
#define TT 256
#define TS 512
#define HH 1024
#define VV 32100
#define VP 32104          // padded to multiple of 8 (keeps float4 alignment)
#define V4 (VV / 4)       // 8025 float4s per row
#define NTHREADS 1024

// Kernel 1: per-row dot products with W_gen.
// rows [0, B*TS)        : e[b,s]  = enc[b,s,:]  . W_gen[0:H]
// rows [B*TS, B*TS+B*TT): g2[b,t] = dec[b,t,:]  . W_gen[H:2H] + b_gen
__global__ __launch_bounds__(256) void precompute_dots(
    const float* __restrict__ dec, const float* __restrict__ enc,
    const float* __restrict__ Wg, const float* __restrict__ bg,
    float* __restrict__ e, float* __restrict__ g2)
{
    int row  = blockIdx.x * 4 + (threadIdx.x >> 6);   // one wave64 per row
    int lane = threadIdx.x & 63;

    const float4* s4;
    const float4* w4;
    float bias = 0.0f;
    float* dst;

    if (row < NB * TS) {
        s4  = (const float4*)(enc + (size_t)row * HH);
        w4  = (const float4*)Wg;
        dst = e + row;
    } else {
        int rr = row - NB * TS;
        if (rr >= NB * TT) return;
        s4   = (const float4*)(dec + (size_t)rr * HH);
        w4   = (const float4*)(Wg + HH);
        bias = bg[0];
        dst  = g2 + rr;
    }

    float acc = 0.0f;
#pragma unroll
    for (int i = lane; i < HH / 4; i += 64) {
        float4 a = s4[i];
        float4 w = w4[i];
        acc += a.x * w.x + a.y * w.y + a.z * w.z + a.w * w.w;
    }
#pragma unroll
    for (int off = 32; off >= 1; off >>= 1)
        acc += __shfl_xor(acc, off);
    if (lane == 0) *dst = acc + bias;
}

// Kernel 2: one block per (b,t) row. Copy-dist in LDS, online softmax,
// fused p_gen, single log-mix output pass.
__global__ __launch_bounds__(NTHREADS) void pointer_gen_kernel(
    const float* __restrict__ attn, const int* __restrict__ ids,
    const float* __restrict__ logits, const float* __restrict__ e,
    const float* __restrict__ g2, float* __restrict__ out)
{
    __shared__ float cp[VP];       // copy distribution for this row (~128.4 KB)
    __shared__ float redd[16];     // p_gen dot partials
    __shared__ float redm[16];     // softmax max partials
    __shared__ float reds[16];     // softmax sum partials
    __shared__ float bcast[3];     // m, Z, p_gen

    const int tid  = threadIdx.x;
    const int bt   = blockIdx.x;       // 0 .. B*TT-1
    const int b    = bt >> 8;          // bt / TT
    const int wid  = tid >> 6;
    const int lane = tid & 63;

    // --- zero the copy distribution ---
    for (int i = tid; i < VP; i += NTHREADS) cp[i] = 0.0f;
    __syncthreads();

    // --- scatter attention mass + p_gen dot partial ---
    float part = 0.0f;
    if (tid < TS) {
        float av = attn[(size_t)bt * TS + tid];
        int   id = ids[b * TS + tid];
        atomicAdd(&cp[id], av);            // LDS atomic; duplicates accumulate
        part = av * e[b * TS + tid];
    }
#pragma unroll
    for (int off = 32; off >= 1; off >>= 1)
        part += __shfl_xor(part, off);
    if (lane == 0) redd[wid] = part;

    // --- online softmax over the logits row (single read pass) ---
    const float4* lp = (const float4*)(logits + (size_t)bt * VV);
    float mi = -3.4e38f, si = 0.0f;
    for (int i = tid; i < V4; i += NTHREADS) {
        float4 v  = lp[i];
        float  m4 = fmaxf(fmaxf(v.x, v.y), fmaxf(v.z, v.w));
        if (m4 > mi) { si *= __expf(mi - m4); mi = m4; }
        si += __expf(v.x - mi) + __expf(v.y - mi) +
              __expf(v.z - mi) + __expf(v.w - mi);
    }
#pragma unroll
    for (int off = 32; off >= 1; off >>= 1) {
        float om = __shfl_xor(mi, off);
        float os = __shfl_xor(si, off);
        float nm = fmaxf(mi, om);
        si = si * __expf(mi - nm) + os * __expf(om - nm);
        mi = nm;
    }
    if (lane == 0) { redm[wid] = mi; reds[wid] = si; }
    __syncthreads();

    if (wid == 0) {
        // p_gen dot across 16 waves
        float d = (lane < 16) ? redd[lane] : 0.0f;
#pragma unroll
        for (int off = 8; off >= 1; off >>= 1)
            d += __shfl_xor(d, off);
        // online (m, s) combine across 16 waves
        float m = (lane < 16) ? redm[lane] : -3.4e38f;
        float s = (lane < 16) ? reds[lane] : 0.0f;
#pragma unroll
        for (int off = 8; off >= 1; off >>= 1) {
            float om = __shfl_xor(m, off);
            float os = __shfl_xor(s, off);
            float nm = fmaxf(m, om);
            s = s * __expf(m - nm) + os * __expf(om - nm);
            m = nm;
        }
        if (lane == 0) {
            float pg = 1.0f / (1.0f + __expf(-(d + g2[bt])));
            bcast[0] = m;
            bcast[1] = s;
            bcast[2] = pg;
        }
    }
    __syncthreads();

    const float m  = bcast[0];
    const float pg = bcast[2];
    const float pz = pg / bcast[1];        // p_gen / Z
    const float q  = 1.0f - pg;

    // --- output pass: log(p*softmax + (1-p)*copy + 1e-12) ---
    const float4* cp4 = (const float4*)cp;
    float4* op = (float4*)(out + (size_t)bt * VV);
    for (int i = tid; i < V4; i += NTHREADS) {
        float4 v = lp[i];                  // second read: L2-resident
        float4 c = cp4[i];                 // contiguous LDS b128, conflict-free
        float4 o;
        o.x = __logf(fmaf(pz, __expf(v.x - m), fmaf(q, c.x, 1e-12f)));
        o.y = __logf(fmaf(pz, __expf(v.y - m), fmaf(q, c.y, 1e-12f)));
        o.z = __logf(fmaf(pz, __expf(v.z - m), fmaf(q, c.z, 1e-12f)));
        o.w = __logf(fmaf(pz, __expf(v.w - m), fmaf(q, c.w, 1e-12f)));
        op[i] = o;
    }
}

extern "C" void kernel_launch(void* const* d_in, const int* in_sizes, int n_in,
                              void* d_out, int out_size, void* d_ws, size_t ws_size,
                              hipStream_t stream) {
    const float* dec    = (const float*)d_in[0];  // (B,TT,H)
    const float* attn   = (const float*)d_in[1];  // (B,TT,TS)
    const float* enc    = (const float*)d_in[2];  // (B,TS,H)
    const float* logits = (const float*)d_in[3];  // (B,TT,V)
    const float* Wg     = (const float*)d_in[4];  // (2H,1)
    const float* bg     = (const float*)d_in[5];  // (1,)
    const int*   ids    = (const int*)d_in[6];    // (B,TS)
    float* out = (float*)d_out;

    float* e  = (float*)d_ws;                 // B*TS floats
    float* g2 = e + NB * TS;                  // B*TT floats

    // 3072 rows total, 4 rows (waves) per 256-thread block
    precompute_dots<<<(NB * TS + NB * TT) / 4, 256, 0, stream>>>(
        dec, enc, Wg, bg, e, g2);

    pointer_gen_kernel<<<NB * TT, NTHREADS, 0, stream>>>(
        attn, ids, logits, e, g2, out);
}

// Round 2
// 68.403 us; speedup vs baseline: 1.0506x; 1.0506x over previous
//
#include <hip/hip_runtime.h>
#include <math.h>

// Problem constants: B=4, T_TGT=256, T_SRC=512, H=1024, V=32100
#define NB 4
#define TT 256
#define TS 512
#define HH 1024
#define VV 32100
#define V4 8025            // float4s per row (32100/4)
#define NCHUNK 4
#define C4 2007            // float4s per chunk (4*2007 = 8028 >= 8025)
#define CF (C4 * 4)        // floats per chunk = 8028 (32.1 KB)
#define NT 512             // threads per block == T_SRC (1 pair per thread)

// Kernel 1: per-row dot products with W_gen.
// rows [0, B*TS)        : e[b,s]  = enc[b,s,:] . W_gen[0:H]
// rows [B*TS, +B*TT)    : g2[b,t] = dec[b,t,:] . W_gen[H:2H] + b_gen
__global__ __launch_bounds__(256) void precompute_dots(
    const float* __restrict__ dec, const float* __restrict__ enc,
    const float* __restrict__ Wg, const float* __restrict__ bg,
    float* __restrict__ e, float* __restrict__ g2)
{
    int row  = blockIdx.x * 4 + (threadIdx.x >> 6);   // one wave64 per row
    int lane = threadIdx.x & 63;

    const float4* s4;
    const float4* w4;
    float bias = 0.0f;
    float* dst;

    if (row < NB * TS) {
        s4  = (const float4*)(enc + (size_t)row * HH);
        w4  = (const float4*)Wg;
        dst = e + row;
    } else {
        int rr = row - NB * TS;
        if (rr >= NB * TT) return;
        s4   = (const float4*)(dec + (size_t)rr * HH);
        w4   = (const float4*)(Wg + HH);
        bias = bg[0];
        dst  = g2 + rr;
    }

    float acc = 0.0f;
#pragma unroll
    for (int i = lane; i < HH / 4; i += 64) {
        float4 a = s4[i];
        float4 w = w4[i];
        acc += a.x * w.x + a.y * w.y + a.z * w.z + a.w * w.w;
    }
#pragma unroll
    for (int off = 32; off >= 1; off >>= 1)
        acc += __shfl_xor(acc, off);
    if (lane == 0) *dst = acc + bias;
}

// Kernel 2: one block per (b,t) row; 512 threads; copy-dist built in
// 4 vocab chunks of 32.1 KB LDS -> 4 blocks/CU, 32 waves/CU.
__global__ __launch_bounds__(NT, 8) void pointer_gen_kernel(
    const float* __restrict__ attn, const int* __restrict__ ids,
    const float* __restrict__ logits, const float* __restrict__ e,
    const float* __restrict__ g2, float* __restrict__ out)
{
    __shared__ float chunk[CF];     // one vocab chunk of the copy dist
    __shared__ float redd[8];       // p_gen dot partials (8 waves)
    __shared__ float redm[8];       // softmax max partials
    __shared__ float reds[8];       // softmax sum partials
    __shared__ float bcast[3];      // m, Z, p_gen

    const int tid  = threadIdx.x;
    const int bt   = blockIdx.x;       // 0 .. B*TT-1
    const int b    = bt >> 8;          // bt / TT
    const int wid  = tid >> 6;
    const int lane = tid & 63;

    // --- this thread's scatter pair (thread tid == source position tid) ---
    const float av  = attn[(size_t)bt * TS + tid];
    const int   idv = ids[b * TS + tid];

    // p_gen dot partial: sum_s attn[s] * (enc[s,:] . W[:H])
    float part = av * e[b * TS + tid];
#pragma unroll
    for (int off = 32; off >= 1; off >>= 1)
        part += __shfl_xor(part, off);
    if (lane == 0) redd[wid] = part;

    // --- pass 1: online softmax over the logits row ---
    const float4* lp = (const float4*)(logits + (size_t)bt * VV);
    float mi = -3.4e38f, si = 0.0f;
    for (int i = tid; i < V4; i += NT) {
        float4 v  = lp[i];
        float  m4 = fmaxf(fmaxf(v.x, v.y), fmaxf(v.z, v.w));
        if (m4 > mi) { si *= __expf(mi - m4); mi = m4; }
        si += __expf(v.x - mi) + __expf(v.y - mi) +
              __expf(v.z - mi) + __expf(v.w - mi);
    }
#pragma unroll
    for (int off = 32; off >= 1; off >>= 1) {
        float om = __shfl_xor(mi, off);
        float os = __shfl_xor(si, off);
        float nm = fmaxf(mi, om);
        si = si * __expf(mi - nm) + os * __expf(om - nm);
        mi = nm;
    }
    if (lane == 0) { redm[wid] = mi; reds[wid] = si; }
    __syncthreads();

    if (wid == 0) {
        float d = (lane < 8) ? redd[lane] : 0.0f;
#pragma unroll
        for (int off = 4; off >= 1; off >>= 1)
            d += __shfl_xor(d, off);
        float m = (lane < 8) ? redm[lane] : -3.4e38f;
        float s = (lane < 8) ? reds[lane] : 0.0f;
#pragma unroll
        for (int off = 4; off >= 1; off >>= 1) {
            float om = __shfl_xor(m, off);
            float os = __shfl_xor(s, off);
            float nm = fmaxf(m, om);
            s = s * __expf(m - nm) + os * __expf(om - nm);
            m = nm;
        }
        if (lane == 0) {
            float pg = 1.0f / (1.0f + __expf(-(d + g2[bt])));
            bcast[0] = m;
            bcast[1] = s;
            bcast[2] = pg;
        }
    }
    __syncthreads();

    const float m  = bcast[0];
    const float pg = bcast[2];
    const float pz = pg / bcast[1];        // p_gen / Z
    const float q  = 1.0f - pg;

    // --- pass 2: per-chunk scatter + log-mix output ---
    float4* op = (float4*)(out + (size_t)bt * VV);
    const float4 z4 = make_float4(0.f, 0.f, 0.f, 0.f);

    for (int c = 0; c < NCHUNK; ++c) {
        const int lo    = c * CF;        // first vocab id in chunk
        const int base4 = c * C4;        // first float4 index in chunk
        const int top4  = (base4 + C4 < V4) ? (base4 + C4) : V4;

        // zero the chunk
        for (int i = tid; i < C4; i += NT)
            ((float4*)chunk)[i] = z4;
        __syncthreads();

        // scatter this thread's pair if it lands in this chunk
        if (idv >= lo && idv < lo + CF)
            atomicAdd(&chunk[idv - lo], av);
        __syncthreads();

        // output for this chunk
        for (int i = base4 + tid; i < top4; i += NT) {
            float4 v = lp[i];                         // L2/L3-resident re-read
            float4 cc = ((const float4*)chunk)[i - base4];
            float4 o;
            o.x = __logf(fmaf(pz, __expf(v.x - m), fmaf(q, cc.x, 1e-12f)));
            o.y = __logf(fmaf(pz, __expf(v.y - m), fmaf(q, cc.y, 1e-12f)));
            o.z = __logf(fmaf(pz, __expf(v.z - m), fmaf(q, cc.z, 1e-12f)));
            o.w = __logf(fmaf(pz, __expf(v.w - m), fmaf(q, cc.w, 1e-12f)));
            op[i] = o;
        }
        __syncthreads();
    }
}

extern "C" void kernel_launch(void* const* d_in, const int* in_sizes, int n_in,
                              void* d_out, int out_size, void* d_ws, size_t ws_size,
                              hipStream_t stream) {
    const float* dec    = (const float*)d_in[0];  // (B,TT,H)
    const float* attn   = (const float*)d_in[1];  // (B,TT,TS)
    const float* enc    = (const float*)d_in[2];  // (B,TS,H)
    const float* logits = (const float*)d_in[3];  // (B,TT,V)
    const float* Wg     = (const float*)d_in[4];  // (2H,1)
    const float* bg     = (const float*)d_in[5];  // (1,)
    const int*   ids    = (const int*)d_in[6];    // (B,TS)
    float* out = (float*)d_out;

    float* e  = (float*)d_ws;                 // B*TS floats
    float* g2 = e + NB * TS;                  // B*TT floats

    precompute_dots<<<(NB * TS + NB * TT) / 4, 256, 0, stream>>>(
        dec, enc, Wg, bg, e, g2);

    pointer_gen_kernel<<<NB * TT, NT, 0, stream>>>(
        attn, ids, logits, e, g2, out);
}

// Round 3
// 60.337 us; speedup vs baseline: 1.1910x; 1.1337x over previous
//
#include <hip/hip_runtime.h>
#include <math.h>

// Problem constants: B=4, T_TGT=256, T_SRC=512, H=1024, V=32100
#define NB 4
#define TT 256
#define TS 512
#define HH 1024
#define VV 32100
#define V4 8025            // float4s per row (32100/4)
#define NCHUNK 4
#define C4 2007            // float4s per chunk (4*2007 = 8028 >= 8025)
#define CF (C4 * 4)        // floats per chunk = 8028 (32.1 KB)
#define NT 512             // threads per block == T_SRC
#define KREG 16            // float4 registers of logits per thread

// Kernel 1: per-row dot products with W_gen.
__global__ __launch_bounds__(256) void precompute_dots(
    const float* __restrict__ dec, const float* __restrict__ enc,
    const float* __restrict__ Wg, const float* __restrict__ bg,
    float* __restrict__ e, float* __restrict__ g2)
{
    int row  = blockIdx.x * 4 + (threadIdx.x >> 6);   // one wave64 per row
    int lane = threadIdx.x & 63;

    const float4* s4;
    const float4* w4;
    float bias = 0.0f;
    float* dst;

    if (row < NB * TS) {
        s4  = (const float4*)(enc + (size_t)row * HH);
        w4  = (const float4*)Wg;
        dst = e + row;
    } else {
        int rr = row - NB * TS;
        if (rr >= NB * TT) return;
        s4   = (const float4*)(dec + (size_t)rr * HH);
        w4   = (const float4*)(Wg + HH);
        bias = bg[0];
        dst  = g2 + rr;
    }

    float acc = 0.0f;
#pragma unroll
    for (int i = lane; i < HH / 4; i += 64) {
        float4 a = s4[i];
        float4 w = w4[i];
        acc += a.x * w.x + a.y * w.y + a.z * w.z + a.w * w.w;
    }
#pragma unroll
    for (int off = 32; off >= 1; off >>= 1)
        acc += __shfl_xor(acc, off);
    if (lane == 0) *dst = acc + bias;
}

// Kernel 2: one block per (b,t) row; logits register-resident (16 float4/thread,
// all loads issued upfront); softmax from registers; chunked LDS copy-dist;
// pass 2 does zero global loads.
__global__ __launch_bounds__(NT, 4) void pointer_gen_kernel(
    const float* __restrict__ attn, const int* __restrict__ ids,
    const float* __restrict__ logits, const float* __restrict__ e,
    const float* __restrict__ g2, float* __restrict__ out)
{
    __shared__ float chunk[CF];     // one vocab chunk of the copy dist (32.1 KB)
    __shared__ float redd[8];       // p_gen dot partials (8 waves)
    __shared__ float redm[8];       // softmax max partials
    __shared__ float reds[8];       // softmax sum partials
    __shared__ float bcast[3];      // m, Z, p_gen

    const int tid  = threadIdx.x;
    const int bt   = blockIdx.x;       // 0 .. B*TT-1
    const int b    = bt >> 8;          // bt / TT
    const int wid  = tid >> 6;
    const int lane = tid & 63;

    // --- scatter pair (thread tid == source position tid) ---
    const float av  = attn[(size_t)bt * TS + tid];
    const int   idv = ids[b * TS + tid];
    float part = av * e[b * TS + tid];

    // --- issue ALL logits loads upfront (clamped index keeps them branch-free)
    const float4* lp = (const float4*)(logits + (size_t)bt * VV);
    float4 v[KREG];
#pragma unroll
    for (int k = 0; k < KREG; ++k) {
        int f  = tid + NT * k;
        int fc = (f < V4) ? f : (V4 - 1);   // only k=15 can clamp
        v[k] = lp[fc];
    }

    // --- p_gen dot wave reduction (overlaps load latency) ---
#pragma unroll
    for (int off = 32; off >= 1; off >>= 1)
        part += __shfl_xor(part, off);
    if (lane == 0) redd[wid] = part;

    // --- per-thread softmax stats from registers (no rescale branch) ---
    float mt = -3.4e38f;
#pragma unroll
    for (int k = 0; k < KREG; ++k) {        // clamped dup can't change max
        float4 w = v[k];
        mt = fmaxf(mt, fmaxf(fmaxf(w.x, w.y), fmaxf(w.z, w.w)));
    }
    float st = 0.0f;
#pragma unroll
    for (int k = 0; k < KREG - 1; ++k) {
        float4 w = v[k];
        st += __expf(w.x - mt) + __expf(w.y - mt) +
              __expf(w.z - mt) + __expf(w.w - mt);
    }
    {   // k = 15: guard against the clamped duplicate
        int f = tid + NT * (KREG - 1);
        if (f < V4) {
            float4 w = v[KREG - 1];
            st += __expf(w.x - mt) + __expf(w.y - mt) +
                  __expf(w.z - mt) + __expf(w.w - mt);
        }
    }
    // wave-level online (m,s) merge
#pragma unroll
    for (int off = 32; off >= 1; off >>= 1) {
        float om = __shfl_xor(mt, off);
        float os = __shfl_xor(st, off);
        float nm = fmaxf(mt, om);
        st = st * __expf(mt - nm) + os * __expf(om - nm);
        mt = nm;
    }
    if (lane == 0) { redm[wid] = mt; reds[wid] = st; }
    __syncthreads();

    if (wid == 0) {
        float d = (lane < 8) ? redd[lane] : 0.0f;
#pragma unroll
        for (int off = 4; off >= 1; off >>= 1)
            d += __shfl_xor(d, off);
        float m = (lane < 8) ? redm[lane] : -3.4e38f;
        float s = (lane < 8) ? reds[lane] : 0.0f;
#pragma unroll
        for (int off = 4; off >= 1; off >>= 1) {
            float om = __shfl_xor(m, off);
            float os = __shfl_xor(s, off);
            float nm = fmaxf(m, om);
            s = s * __expf(m - nm) + os * __expf(om - nm);
            m = nm;
        }
        if (lane == 0) {
            float pg = 1.0f / (1.0f + __expf(-(d + g2[bt])));
            bcast[0] = m;
            bcast[1] = s;
            bcast[2] = pg;
        }
    }
    __syncthreads();

    const float m  = bcast[0];
    const float pg = bcast[2];
    const float pz = pg / bcast[1];        // p_gen / Z
    const float q  = 1.0f - pg;

    // --- pass 2: per-chunk scatter + log-mix output, NO global loads ---
    float4* op = (float4*)(out + (size_t)bt * VV);
    const float4 z4 = make_float4(0.f, 0.f, 0.f, 0.f);

#pragma unroll
    for (int c = 0; c < NCHUNK; ++c) {
        const int flo = C4 * c;            // first float4 index in chunk
        const int fhi = flo + C4;

        // zero the chunk
#pragma unroll
        for (int i = 0; i < 4; ++i) {
            int j = tid + NT * i;
            if (j < C4) ((float4*)chunk)[j] = z4;
        }
        __syncthreads();

        // scatter this thread's pair if it lands in this chunk
        if (idv >= 4 * flo && idv < 4 * fhi)
            atomicAdd(&chunk[idv - 4 * flo], av);
        __syncthreads();

        // output from registers + LDS chunk
#pragma unroll
        for (int k = 0; k < KREG; ++k) {
            // compile-time: does [NT*k, NT*k+NT-1] intersect [flo, fhi)?
            if (NT * k + NT - 1 >= flo && NT * k < fhi) {
                int f = tid + NT * k;
                if (f >= flo && f < fhi && f < V4) {
                    float4 cc = ((const float4*)chunk)[f - flo];
                    float4 w  = v[k];
                    float4 o;
                    o.x = __logf(fmaf(pz, __expf(w.x - m), fmaf(q, cc.x, 1e-12f)));
                    o.y = __logf(fmaf(pz, __expf(w.y - m), fmaf(q, cc.y, 1e-12f)));
                    o.z = __logf(fmaf(pz, __expf(w.z - m), fmaf(q, cc.z, 1e-12f)));
                    o.w = __logf(fmaf(pz, __expf(w.w - m), fmaf(q, cc.w, 1e-12f)));
                    op[f] = o;
                }
            }
        }
        __syncthreads();
    }
}

extern "C" void kernel_launch(void* const* d_in, const int* in_sizes, int n_in,
                              void* d_out, int out_size, void* d_ws, size_t ws_size,
                              hipStream_t stream) {
    const float* dec    = (const float*)d_in[0];  // (B,TT,H)
    const float* attn   = (const float*)d_in[1];  // (B,TT,TS)
    const float* enc    = (const float*)d_in[2];  // (B,TS,H)
    const float* logits = (const float*)d_in[3];  // (B,TT,V)
    const float* Wg     = (const float*)d_in[4];  // (2H,1)
    const float* bg     = (const float*)d_in[5];  // (1,)
    const int*   ids    = (const int*)d_in[6];    // (B,TS)
    float* out = (float*)d_out;

    float* e  = (float*)d_ws;                 // B*TS floats
    float* g2 = e + NB * TS;                  // B*TT floats

    precompute_dots<<<(NB * TS + NB * TT) / 4, 256, 0, stream>>>(
        dec, enc, Wg, bg, e, g2);

    pointer_gen_kernel<<<NB * TT, NT, 0, stream>>>(
        attn, ids, logits, e, g2, out);
}